// Round 9
// baseline (403.693 us; speedup 1.0000x reference)
//
#include <hip/hip_runtime.h>
#include <hip/hip_bf16.h>
#include <math.h>

#define NNODES 20000
#define MPAD 20096            // padded to multiple of 128
#define NEDGES 320000
#define HIDC 256
#define DINC 512
#define NHEAD 8
#define HDIM 32
#define SCALE 0.17677669529663687f

typedef __attribute__((ext_vector_type(8))) short short8;
typedef __attribute__((ext_vector_type(4))) short svec4;
typedef __attribute__((ext_vector_type(4))) float f32x4;

__device__ __forceinline__ void gload_lds16(const void* g, void* l) {
    __builtin_amdgcn_global_load_lds(
        (const __attribute__((address_space(1))) unsigned int*)g,
        (__attribute__((address_space(3))) unsigned int*)l, 16, 0, 0);
}

__device__ __forceinline__ float bfbits(unsigned short u) {
    return __uint_as_float(((unsigned)u) << 16);
}

// ---------------------------------------------------------------------------
// concat h_in = [x | h] -> bf16 [MPAD][512], pad rows zeroed
__global__ __launch_bounds__(256) void concat_xh(const float* __restrict__ x,
                                                 const float* __restrict__ h,
                                                 __hip_bfloat16* __restrict__ out) {
    int i = blockIdx.x * 256 + threadIdx.x;
    int total = MPAD * DINC;
    if (i >= total) return;
    int row = i >> 9;
    int col = i & 511;
    float v = 0.f;
    if (row < NNODES)
        v = (col < HIDC) ? x[row * HIDC + col] : h[row * HIDC + (col - HIDC)];
    out[i] = __float2bfloat16(v);
}

// ---------------------------------------------------------------------------
// weight transpose+convert: W[512][256] f32 -> Wt[256][512] bf16 (12 matrices)
struct WPtrs { const float* p[12]; };

__global__ __launch_bounds__(256) void transpose_w(WPtrs wp, __hip_bfloat16* __restrict__ out) {
    __shared__ float t[64][65];
    int mat = blockIdx.z;
    int kt = blockIdx.x * 64;
    int nt = blockIdx.y * 64;
    const float* W = wp.p[mat];
    int c = threadIdx.x & 63, r4 = threadIdx.x >> 6;
#pragma unroll
    for (int rr = 0; rr < 16; ++rr) {
        int k_l = r4 + rr * 4;
        t[k_l][c] = W[(kt + k_l) * HIDC + nt + c];
    }
    __syncthreads();
#pragma unroll
    for (int rr = 0; rr < 16; ++rr) {
        int n_l = r4 + rr * 4;
        out[mat * (HIDC * DINC) + (nt + n_l) * DINC + kt + c] =
            __float2bfloat16(t[c][n_l]);
    }
}

// ---------------------------------------------------------------------------
// CSR build (stores src node directly: csrc[idx] = src[e])
__global__ __launch_bounds__(256) void count_deg(const int* __restrict__ dst,
                                                 int* __restrict__ deg) {
    int e = blockIdx.x * 256 + threadIdx.x;
    if (e >= NEDGES) return;
    atomicAdd(&deg[dst[e]], 1);
}

__global__ __launch_bounds__(1024) void exscan(const int* __restrict__ deg,
                                               int* __restrict__ rowptr,
                                               int* __restrict__ pos) {
    __shared__ int sdata[1024];
    __shared__ int s_carry;
    const int tid = threadIdx.x;
    if (tid == 0) { s_carry = 0; rowptr[0] = 0; }
    __syncthreads();
    for (int base = 0; base < NNODES; base += 1024) {
        int i = base + tid;
        int v = (i < NNODES) ? deg[i] : 0;
        sdata[tid] = v;
        __syncthreads();
        for (int off = 1; off < 1024; off <<= 1) {
            int t = (tid >= off) ? sdata[tid - off] : 0;
            __syncthreads();
            sdata[tid] += t;
            __syncthreads();
        }
        int incl = sdata[tid];
        int carry = s_carry;
        if (i < NNODES) {
            int ex = carry + incl - v;
            rowptr[i] = ex;
            pos[i] = ex;
            if (i == NNODES - 1) rowptr[NNODES] = carry + incl;
        }
        __syncthreads();
        if (tid == 1023) s_carry = carry + incl;
        __syncthreads();
    }
}

__global__ __launch_bounds__(256) void scatter_src(const int* __restrict__ src,
                                                   const int* __restrict__ dst,
                                                   int* __restrict__ pos,
                                                   int* __restrict__ csrc) {
    int e = blockIdx.x * 256 + threadIdx.x;
    if (e >= NEDGES) return;
    int idx = atomicAdd(&pos[dst[e]], 1);
    csrc[idx] = src[e];
}

// ---------------------------------------------------------------------------
// MFMA GEMM, m97-faithful single-buffer 32KB LDS (3+ blocks/CU) + XCD-contiguous
// mapping for A-tile L2 reuse. Per-slot output pointer + ldc + bf16 mask.
struct GemmArgs { const float* bias[8]; void* C[8]; int ldc[8]; unsigned bf16mask; };

template <int NZ>
__global__ __launch_bounds__(256) void gemm_mfma(
    const __hip_bfloat16* __restrict__ A,
    const __hip_bfloat16* __restrict__ WtBase,
    GemmArgs ga) {
    __shared__ __align__(16) char smem[32768];   // A 16KB | B 16KB

    int nwg = gridDim.x;
    int per = nwg >> 3;
    int lin = (blockIdx.x & 7) * per + (blockIdx.x >> 3);  // XCD-contiguous
    int bmIdx = lin / NZ;
    int nz = lin % NZ;
    int bm = bmIdx * 128;
    int bn = (nz & 1) * 128;
    int z = nz >> 1;

    const __hip_bfloat16* Bt = WtBase + (size_t)z * (HIDC * DINC);
    const float* bias = ga.bias[z];
    void* Cv = ga.C[z];
    int ldc = ga.ldc[z];
    bool isb = (ga.bf16mask >> z) & 1;

    int tid = threadIdx.x;
    int wave = tid >> 6, lane = tid & 63;
    int lrow = lane >> 3;                 // 0..7
    int lcol = (lane & 7) ^ lrow;         // pre-swizzled source column unit

    int wr = wave >> 1, wc = wave & 1;
    int m_base = wr * 64, n_base = wc * 64;
    int l16 = lane & 15, lk = lane >> 4;

    char* As = smem;
    char* Bs = smem + 16384;

    f32x4 acc[4][4] = {};

    for (int kt = 0; kt < DINC; kt += 64) {
#pragma unroll
        for (int c4 = 0; c4 < 4; ++c4) {
            int c = wave * 4 + c4;
            gload_lds16(&A[(size_t)(bm + c * 8 + lrow) * DINC + kt + lcol * 8],
                        As + c * 1024);
        }
#pragma unroll
        for (int c4 = 0; c4 < 4; ++c4) {
            int c = wave * 4 + c4;
            gload_lds16(&Bt[(size_t)(bn + c * 8 + lrow) * DINC + kt + lcol * 8],
                        Bs + c * 1024);
        }
        __syncthreads();
#pragma unroll
        for (int kk = 0; kk < 2; ++kk) {
            short8 af[4], bf[4];
#pragma unroll
            for (int f = 0; f < 4; ++f) {
                int row = m_base + f * 16 + l16;
                int lin2 = row * 128 + (kk * 32 + lk * 8) * 2;
                af[f] = *(const short8*)(As + (lin2 ^ ((row & 7) << 4)));
                int rowb = n_base + f * 16 + l16;
                int linb = rowb * 128 + (kk * 32 + lk * 8) * 2;
                bf[f] = *(const short8*)(Bs + (linb ^ ((rowb & 7) << 4)));
            }
#pragma unroll
            for (int i = 0; i < 4; ++i)
#pragma unroll
                for (int j = 0; j < 4; ++j)
                    acc[i][j] = __builtin_amdgcn_mfma_f32_16x16x32_bf16(
                        af[i], bf[j], acc[i][j], 0, 0, 0);
        }
        __syncthreads();
    }

#pragma unroll
    for (int i = 0; i < 4; ++i) {
#pragma unroll
        for (int j = 0; j < 4; ++j) {
            int n = bn + n_base + j * 16 + l16;
            float bia = bias[n];
#pragma unroll
            for (int r = 0; r < 4; ++r) {
                int m = bm + m_base + i * 16 + lk * 4 + r;
                if (m < NNODES) {
                    float val = acc[i][j][r] + bia;
                    if (isb)
                        ((__hip_bfloat16*)Cv)[(size_t)m * ldc + n] = __float2bfloat16(val);
                    else
                        ((float*)Cv)[(size_t)m * ldc + n] = val;
                }
            }
        }
    }
}

// ---------------------------------------------------------------------------
// Wave-per-node fused z+r attention, 2-deep software pipeline.
// K2/V2 gate-packed [node][gate*256+ch]; S bf16.
__global__ __launch_bounds__(256) void attn_zr(
    const __hip_bfloat16* __restrict__ Qz, const __hip_bfloat16* __restrict__ Qr,
    const __hip_bfloat16* __restrict__ K2, const __hip_bfloat16* __restrict__ V2,
    const __hip_bfloat16* __restrict__ Sz, const __hip_bfloat16* __restrict__ Sr,
    const int* __restrict__ rowptr, const int* __restrict__ csrc,
    const float* __restrict__ h,
    float* __restrict__ Zout, __hip_bfloat16* __restrict__ abuf) {
    int lane = threadIdx.x & 63;
    int node = blockIdx.x * 4 + (threadIdx.x >> 6);

    int eA = lane >> 4;           // phase A edge slot
    int gA = (lane >> 3) & 1;     // phase A gate
    int hA = lane & 7;            // phase A head
    int gC = lane >> 5;           // phase C gate
    int cL = lane & 31;           // phase C channel group
    int cBase = cL * 8;
    int hC = cL >> 2;
    int wsrc = gC * 8 + hC;
    size_t kOff = (size_t)gA * 256 + hA * 32;   // within 512-ch packed row
    size_t vOff = (size_t)gC * 256 + cBase;

    const __hip_bfloat16* Qa = gA ? Qr : Qz;
    short8 qs[4];
    {
        const short8* Qrow = (const short8*)&Qa[(size_t)node * HIDC + hA * 32];
        qs[0] = Qrow[0]; qs[1] = Qrow[1]; qs[2] = Qrow[2]; qs[3] = Qrow[3];
    }

    int beg = rowptr[node], end = rowptr[node + 1];
    float acc[8] = {};
    float s_priv = 0.f;

    auto issueKV = [&](int snL, short8* k, short8* v) {
        int mySn = __shfl(snL, eA);
        const short8* Kp = (const short8*)&K2[(size_t)mySn * 512 + kOff];
        k[0] = Kp[0]; k[1] = Kp[1]; k[2] = Kp[2]; k[3] = Kp[3];
#pragma unroll
        for (int e = 0; e < 4; ++e) {
            int sne = __shfl(snL, e);
            v[e] = *(const short8*)&V2[(size_t)sne * 512 + vOff];
        }
    };
    auto computeC = [&](int snL, int cnt, short8* k, short8* v) {
        float w = 0.f;
        if (eA < cnt) {
            float dot = 0.f;
#pragma unroll
            for (int i = 0; i < 4; ++i) {
                short8 kv = k[i], qv = qs[i];
#pragma unroll
                for (int j = 0; j < 8; ++j)
                    dot += bfbits((unsigned short)qv[j]) * bfbits((unsigned short)kv[j]);
            }
            w = __expf(dot * SCALE);
        }
#pragma unroll
        for (int e = 0; e < 4; ++e) {
            float we = __shfl(w, e * 16 + wsrc);
            if (e < cnt) {
                short8 vv = v[e];
#pragma unroll
                for (int j = 0; j < 8; ++j) acc[j] += we * bfbits((unsigned short)vv[j]);
                s_priv += we;
            }
        }
    };

    if (beg < end) {
        short8 kA[4], vA[4], kB[4], vB[4];
        int baseA = beg;
        int cntA = min(4, end - baseA);
        int snLA = (lane < cntA) ? csrc[baseA + lane] : 0;
        issueKV(snLA, kA, vA);
        int baseB = baseA + 4, cntB = 0, snLB = 0;
        if (baseB < end) { cntB = min(4, end - baseB); snLB = (lane < cntB) ? csrc[baseB + lane] : 0; }
        for (;;) {
            if (baseB < end) issueKV(snLB, kB, vB);
            int baseN = baseB + 4, cntN = 0, snLN = 0;
            if (baseN < end) { cntN = min(4, end - baseN); snLN = (lane < cntN) ? csrc[baseN + lane] : 0; }
            computeC(snLA, cntA, kA, vA);
            if (baseB >= end) break;
            if (baseN < end) issueKV(snLN, kA, vA);
            int baseN2 = baseN + 4, cntN2 = 0, snLN2 = 0;
            if (baseN2 < end) { cntN2 = min(4, end - baseN2); snLN2 = (lane < cntN2) ? csrc[baseN2 + lane] : 0; }
            computeC(snLB, cntB, kB, vB);
            if (baseN >= end) break;
            baseA = baseN; cntA = cntN; snLA = snLN;
            baseB = baseN2; cntB = cntN2; snLB = snLN2;
        }
    }

    float inv = 1.f / (s_priv + 1e-16f);
    const __hip_bfloat16* Sx = gC ? Sr : Sz;
    short8 sv = *(const short8*)&Sx[(size_t)node * HIDC + cBase];
    float g[8];
#pragma unroll
    for (int j = 0; j < 8; ++j) {
        float p = acc[j] * inv + bfbits((unsigned short)sv[j]);
        g[j] = 1.f / (1.f + __expf(-p));
    }
    if (gC == 0) {
        float* Zp = &Zout[(size_t)node * HIDC + cBase];
#pragma unroll
        for (int j = 0; j < 8; ++j) Zp[j] = g[j];
    } else {
        const float* hp = &h[(size_t)node * HIDC + cBase];
        __hip_bfloat16* ap = &abuf[(size_t)node * DINC + HIDC + cBase];
#pragma unroll
        for (int j = 0; j < 8; ++j) ap[j] = __float2bfloat16(g[j] * hp[j]);
    }
}

// ---------------------------------------------------------------------------
// Wave-per-node c-gate attention + GRU combine, 2-deep pipeline. S bf16.
__global__ __launch_bounds__(256) void attn_c(
    const __hip_bfloat16* __restrict__ Q, const __hip_bfloat16* __restrict__ K,
    const __hip_bfloat16* __restrict__ V, const __hip_bfloat16* __restrict__ S,
    const int* __restrict__ rowptr, const int* __restrict__ csrc,
    const float* __restrict__ zbuf, const float* __restrict__ h,
    float* __restrict__ out) {
    int lane = threadIdx.x & 63;
    int node = blockIdx.x * 4 + (threadIdx.x >> 6);

    int eA = lane >> 3;           // phase A edge slot (0..7)
    int hA = lane & 7;            // phase A head
    int cBase = lane * 4;         // phase C: 4 channels per lane
    int hC = lane >> 3;           // head of phase C channels

    short8 qs[4];
    {
        const short8* Qrow = (const short8*)&Q[(size_t)node * HIDC + hA * 32];
        qs[0] = Qrow[0]; qs[1] = Qrow[1]; qs[2] = Qrow[2]; qs[3] = Qrow[3];
    }

    int beg = rowptr[node], end = rowptr[node + 1];
    float acc[4] = {};
    float s_priv = 0.f;

    auto issueKV = [&](int snL, short8* k, svec4* v) {
        int mySn = __shfl(snL, eA);
        const short8* Kp = (const short8*)&K[(size_t)mySn * HIDC + hA * 32];
        k[0] = Kp[0]; k[1] = Kp[1]; k[2] = Kp[2]; k[3] = Kp[3];
#pragma unroll
        for (int e = 0; e < 8; ++e) {
            int sne = __shfl(snL, e);
            v[e] = *(const svec4*)&V[(size_t)sne * HIDC + cBase];
        }
    };
    auto computeC = [&](int snL, int cnt, short8* k, svec4* v) {
        float w = 0.f;
        if (eA < cnt) {
            float dot = 0.f;
#pragma unroll
            for (int i = 0; i < 4; ++i) {
                short8 kv = k[i], qv = qs[i];
#pragma unroll
                for (int j = 0; j < 8; ++j)
                    dot += bfbits((unsigned short)qv[j]) * bfbits((unsigned short)kv[j]);
            }
            w = __expf(dot * SCALE);
        }
#pragma unroll
        for (int e = 0; e < 8; ++e) {
            float we = __shfl(w, e * 8 + hC);
            if (e < cnt) {
                svec4 vv = v[e];
#pragma unroll
                for (int j = 0; j < 4; ++j) acc[j] += we * bfbits((unsigned short)vv[j]);
                s_priv += we;
            }
        }
    };

    if (beg < end) {
        short8 kA[4], kB[4];
        svec4 vA[8], vB[8];
        int baseA = beg;
        int cntA = min(8, end - baseA);
        int snLA = (lane < cntA) ? csrc[baseA + lane] : 0;
        issueKV(snLA, kA, vA);
        int baseB = baseA + 8, cntB = 0, snLB = 0;
        if (baseB < end) { cntB = min(8, end - baseB); snLB = (lane < cntB) ? csrc[baseB + lane] : 0; }
        for (;;) {
            if (baseB < end) issueKV(snLB, kB, vB);
            int baseN = baseB + 8, cntN = 0, snLN = 0;
            if (baseN < end) { cntN = min(8, end - baseN); snLN = (lane < cntN) ? csrc[baseN + lane] : 0; }
            computeC(snLA, cntA, kA, vA);
            if (baseB >= end) break;
            if (baseN < end) issueKV(snLN, kA, vA);
            int baseN2 = baseN + 8, cntN2 = 0, snLN2 = 0;
            if (baseN2 < end) { cntN2 = min(8, end - baseN2); snLN2 = (lane < cntN2) ? csrc[baseN2 + lane] : 0; }
            computeC(snLB, cntB, kB, vB);
            if (baseN >= end) break;
            baseA = baseN; cntA = cntN; snLA = snLN;
            baseB = baseN2; cntB = cntN2; snLB = snLN2;
        }
    }

    float inv = 1.f / (s_priv + 1e-16f);
    svec4 sv = *(const svec4*)&S[(size_t)node * HIDC + cBase];
    f32x4 o;
#pragma unroll
    for (int j = 0; j < 4; ++j) {
        float pre = acc[j] * inv + bfbits((unsigned short)sv[j]);
        float ht = tanhf(pre);
        float zz = zbuf[(size_t)node * HIDC + cBase + j];
        float hh = h[(size_t)node * HIDC + cBase + j];
        o[j] = zz * hh + (1.f - zz) * ht;
    }
    *(f32x4*)&out[(size_t)node * HIDC + cBase] = o;
}

// ---------------------------------------------------------------------------
extern "C" void kernel_launch(void* const* d_in, const int* in_sizes, int n_in,
                              void* d_out, int out_size, void* d_ws, size_t ws_size,
                              hipStream_t stream) {
    const float* x = (const float*)d_in[0];
    const float* h = (const float*)d_in[1];
    const int* ei = (const int*)d_in[2];
    const float* Wf[3][4];
    const float* B[3][4];
    for (int g = 0; g < 3; ++g)
        for (int p = 0; p < 4; ++p) {
            Wf[g][p] = (const float*)d_in[3 + g * 8 + p * 2];
            B[g][p] = (const float*)d_in[3 + g * 8 + p * 2 + 1];
        }

    char* ws = (char*)d_ws;
    size_t off = 0;
    auto alloc = [&](size_t bytes) {
        void* p = ws + off;
        off = (off + bytes + 255) & ~(size_t)255;
        return p;
    };
    __hip_bfloat16* Abuf = (__hip_bfloat16*)alloc((size_t)MPAD * DINC * 2);
    __hip_bfloat16* Wt = (__hip_bfloat16*)alloc((size_t)12 * HIDC * DINC * 2);
    __hip_bfloat16* Qz = (__hip_bfloat16*)alloc((size_t)NNODES * HIDC * 2);
    __hip_bfloat16* Qr = (__hip_bfloat16*)alloc((size_t)NNODES * HIDC * 2);
    __hip_bfloat16* K2 = (__hip_bfloat16*)alloc((size_t)NNODES * 512 * 2);  // Kz|Kr packed
    __hip_bfloat16* V2 = (__hip_bfloat16*)alloc((size_t)NNODES * 512 * 2);  // Vz|Vr packed
    __hip_bfloat16* Sz = (__hip_bfloat16*)alloc((size_t)NNODES * HIDC * 2);
    __hip_bfloat16* Sr = (__hip_bfloat16*)alloc((size_t)NNODES * HIDC * 2);
    float* Zb = (float*)alloc((size_t)NNODES * HIDC * 4);
    int* deg = (int*)alloc((size_t)NNODES * 4);
    int* rowptr = (int*)alloc((size_t)(NNODES + 1) * 4);
    int* pos = (int*)alloc((size_t)NNODES * 4);
    int* csrc = (int*)alloc((size_t)NEDGES * 4);

    const int* srcArr = ei;
    const int* dstArr = ei + NEDGES;

    WPtrs wp;
    for (int g = 0; g < 3; ++g)
        for (int p = 0; p < 4; ++p) wp.p[g * 4 + p] = Wf[g][p];

    (void)hipMemsetAsync(deg, 0, NNODES * sizeof(int), stream);
    concat_xh<<<(MPAD * DINC + 255) / 256, 256, 0, stream>>>(x, h, Abuf);
    transpose_w<<<dim3(8, 4, 12), 256, 0, stream>>>(wp, Wt);
    count_deg<<<(NEDGES + 255) / 256, 256, 0, stream>>>(dstArr, deg);
    exscan<<<1, 1024, 0, stream>>>(deg, rowptr, pos);
    scatter_src<<<(NEDGES + 255) / 256, 256, 0, stream>>>(srcArr, dstArr, pos, csrc);

    // GEMM launch A: z+r gates, 8 matrices; grid = 157 * 16 = 2512 (div by 8)
    {
        GemmArgs ga;
        for (int p = 0; p < 4; ++p) { ga.bias[p] = B[0][p]; ga.bias[4 + p] = B[1][p]; }
        ga.C[0] = Qz;        ga.ldc[0] = 256;
        ga.C[1] = K2;        ga.ldc[1] = 512;   // Kz -> packed row low half
        ga.C[2] = V2;        ga.ldc[2] = 512;
        ga.C[3] = Sz;        ga.ldc[3] = 256;
        ga.C[4] = Qr;        ga.ldc[4] = 256;
        ga.C[5] = K2 + 256;  ga.ldc[5] = 512;   // Kr -> packed row high half
        ga.C[6] = V2 + 256;  ga.ldc[6] = 512;
        ga.C[7] = Sr;        ga.ldc[7] = 256;
        ga.bf16mask = 0xFF;  // everything bf16 now (S included)
        gemm_mfma<16><<<(MPAD / 128) * 16, 256, 0, stream>>>(Abuf, Wt, ga);
    }
    attn_zr<<<NNODES / 4, 256, 0, stream>>>(Qz, Qr, K2, V2, Sz, Sr,
                                            rowptr, csrc, h, Zb, Abuf);
    // GEMM launch B: c gate, 4 matrices; grid = 157 * 8 = 1256 (div by 8)
    {
        GemmArgs ga;
        for (int p = 0; p < 8; ++p) { ga.bias[p] = B[2][p & 3]; ga.C[p] = nullptr; ga.ldc[p] = 256; }
        ga.C[0] = Qz; ga.C[1] = K2; ga.C[2] = V2; ga.C[3] = Sz;   // reuse, ld 256 dense
        ga.bf16mask = 0xFF;
        gemm_mfma<8><<<(MPAD / 128) * 8, 256, 0, stream>>>(
            Abuf, Wt + (size_t)8 * HIDC * DINC, ga);
    }
    attn_c<<<NNODES / 4, 256, 0, stream>>>(Qz, K2, V2, Sz, rowptr, csrc,
                                           Zb, h, (float*)d_out);
}

// Round 10
// 366.075 us; speedup vs baseline: 1.1028x; 1.1028x over previous
//
#include <hip/hip_runtime.h>
#include <hip/hip_bf16.h>
#include <math.h>

#define NNODES 20000
#define MPAD 20096            // padded to multiple of 128
#define NEDGES 320000
#define HIDC 256
#define DINC 512
#define NHEAD 8
#define HDIM 32
#define SCALE 0.17677669529663687f

typedef __attribute__((ext_vector_type(8))) short short8;
typedef __attribute__((ext_vector_type(4))) short svec4;
typedef __attribute__((ext_vector_type(4))) float f32x4;

__device__ __forceinline__ void gload_lds16(const void* g, void* l) {
    __builtin_amdgcn_global_load_lds(
        (const __attribute__((address_space(1))) unsigned int*)g,
        (__attribute__((address_space(3))) unsigned int*)l, 16, 0, 0);
}

__device__ __forceinline__ float bfbits(unsigned short u) {
    return __uint_as_float(((unsigned)u) << 16);
}

// ---------------------------------------------------------------------------
// concat h_in = [x | h] -> bf16 [MPAD][512], pad rows zeroed
__global__ __launch_bounds__(256) void concat_xh(const float* __restrict__ x,
                                                 const float* __restrict__ h,
                                                 __hip_bfloat16* __restrict__ out) {
    int i = blockIdx.x * 256 + threadIdx.x;
    int total = MPAD * DINC;
    if (i >= total) return;
    int row = i >> 9;
    int col = i & 511;
    float v = 0.f;
    if (row < NNODES)
        v = (col < HIDC) ? x[row * HIDC + col] : h[row * HIDC + (col - HIDC)];
    out[i] = __float2bfloat16(v);
}

// ---------------------------------------------------------------------------
// weight transpose+convert: W[512][256] f32 -> Wt[256][512] bf16 (12 matrices)
struct WPtrs { const float* p[12]; };

__global__ __launch_bounds__(256) void transpose_w(WPtrs wp, __hip_bfloat16* __restrict__ out) {
    __shared__ float t[64][65];
    int mat = blockIdx.z;
    int kt = blockIdx.x * 64;
    int nt = blockIdx.y * 64;
    const float* W = wp.p[mat];
    int c = threadIdx.x & 63, r4 = threadIdx.x >> 6;
#pragma unroll
    for (int rr = 0; rr < 16; ++rr) {
        int k_l = r4 + rr * 4;
        t[k_l][c] = W[(kt + k_l) * HIDC + nt + c];
    }
    __syncthreads();
#pragma unroll
    for (int rr = 0; rr < 16; ++rr) {
        int n_l = r4 + rr * 4;
        out[mat * (HIDC * DINC) + (nt + n_l) * DINC + kt + c] =
            __float2bfloat16(t[c][n_l]);
    }
}

// ---------------------------------------------------------------------------
// CSR build (stores src node directly: csrc[idx] = src[e])
__global__ __launch_bounds__(256) void count_deg(const int* __restrict__ dst,
                                                 int* __restrict__ deg) {
    int e = blockIdx.x * 256 + threadIdx.x;
    if (e >= NEDGES) return;
    atomicAdd(&deg[dst[e]], 1);
}

// wave-shuffle exclusive scan: 4 barriers per 1024-chunk (was ~20)
__global__ __launch_bounds__(1024) void exscan(const int* __restrict__ deg,
                                               int* __restrict__ rowptr,
                                               int* __restrict__ pos) {
    __shared__ int wsum[16];
    __shared__ int s_carry;
    const int tid = threadIdx.x;
    const int lane = tid & 63, wid = tid >> 6;
    if (tid == 0) { s_carry = 0; rowptr[0] = 0; }
    __syncthreads();
    for (int base = 0; base < NNODES; base += 1024) {
        int i = base + tid;
        int v = (i < NNODES) ? deg[i] : 0;
        int s = v;
#pragma unroll
        for (int off = 1; off < 64; off <<= 1) {
            int t = __shfl_up(s, off);
            if (lane >= off) s += t;
        }
        if (lane == 63) wsum[wid] = s;
        __syncthreads();
        if (wid == 0 && lane < 16) {
            int ws = wsum[lane];
#pragma unroll
            for (int off = 1; off < 16; off <<= 1) {
                int t = __shfl_up(ws, off);
                if (lane >= off) ws += t;
            }
            wsum[lane] = ws;
        }
        __syncthreads();
        int woff = (wid > 0) ? wsum[wid - 1] : 0;
        int incl = s + woff + s_carry;
        if (i < NNODES) {
            rowptr[i] = incl - v;
            pos[i] = incl - v;
            if (i == NNODES - 1) rowptr[NNODES] = incl;
        }
        __syncthreads();
        if (tid == 1023) s_carry = incl;
        __syncthreads();
    }
}

__global__ __launch_bounds__(256) void scatter_src(const int* __restrict__ src,
                                                   const int* __restrict__ dst,
                                                   int* __restrict__ pos,
                                                   int* __restrict__ csrc) {
    int e = blockIdx.x * 256 + threadIdx.x;
    if (e >= NEDGES) return;
    int idx = atomicAdd(&pos[dst[e]], 1);
    csrc[idx] = src[e];
}

// ---------------------------------------------------------------------------
// MFMA GEMM, double-buffered LDS + counted vmcnt (R8 structure, best measured);
// XCD-contiguous mapping for A-tile L2 reuse; per-slot C pointer + ldc + bf16.
struct GemmArgs { const float* bias[8]; void* C[8]; int ldc[8]; unsigned bf16mask; };

template <int NZ>
__global__ __launch_bounds__(256) void gemm_mfma(
    const __hip_bfloat16* __restrict__ A,
    const __hip_bfloat16* __restrict__ WtBase,
    GemmArgs ga) {
    __shared__ __align__(16) char smem[2][32768];  // [buf][A 16KB | B 16KB]

    int nwg = gridDim.x;
    int per = nwg >> 3;
    int lin = (blockIdx.x & 7) * per + (blockIdx.x >> 3);  // XCD-contiguous
    int bmIdx = lin / NZ;
    int nz = lin % NZ;
    int bm = bmIdx * 128;
    int bn = (nz & 1) * 128;
    int z = nz >> 1;

    const __hip_bfloat16* Bt = WtBase + (size_t)z * (HIDC * DINC);
    const float* bias = ga.bias[z];
    void* Cv = ga.C[z];
    int ldc = ga.ldc[z];
    bool isb = (ga.bf16mask >> z) & 1;

    int tid = threadIdx.x;
    int wave = tid >> 6, lane = tid & 63;
    int lrow = lane >> 3;                 // 0..7
    int lcol = (lane & 7) ^ lrow;         // pre-swizzled source column unit

    int wr = wave >> 1, wc = wave & 1;
    int m_base = wr * 64, n_base = wc * 64;
    int l16 = lane & 15, lk = lane >> 4;

    f32x4 acc[4][4] = {};

    auto stage = [&](int buf, int kt) {
        char* As = smem[buf];
        char* Bs = smem[buf] + 16384;
#pragma unroll
        for (int c4 = 0; c4 < 4; ++c4) {
            int c = wave * 4 + c4;
            gload_lds16(&A[(size_t)(bm + c * 8 + lrow) * DINC + kt + lcol * 8],
                        As + c * 1024);
        }
#pragma unroll
        for (int c4 = 0; c4 < 4; ++c4) {
            int c = wave * 4 + c4;
            gload_lds16(&Bt[(size_t)(bn + c * 8 + lrow) * DINC + kt + lcol * 8],
                        Bs + c * 1024);
        }
    };

    auto compute = [&](int buf) {
        char* As = smem[buf];
        char* Bs = smem[buf] + 16384;
#pragma unroll
        for (int kk = 0; kk < 2; ++kk) {
            short8 af[4], bf[4];
#pragma unroll
            for (int f = 0; f < 4; ++f) {
                int row = m_base + f * 16 + l16;
                int lin2 = row * 128 + (kk * 32 + lk * 8) * 2;
                af[f] = *(const short8*)(As + (lin2 ^ ((row & 7) << 4)));
                int rowb = n_base + f * 16 + l16;
                int linb = rowb * 128 + (kk * 32 + lk * 8) * 2;
                bf[f] = *(const short8*)(Bs + (linb ^ ((rowb & 7) << 4)));
            }
#pragma unroll
            for (int i = 0; i < 4; ++i)
#pragma unroll
                for (int j = 0; j < 4; ++j)
                    acc[i][j] = __builtin_amdgcn_mfma_f32_16x16x32_bf16(
                        af[i], bf[j], acc[i][j], 0, 0, 0);
        }
    };

    stage(0, 0);
#pragma unroll
    for (int t = 0; t < 8; ++t) {
        int cur = t & 1;
        if (t < 7) {
            stage(cur ^ 1, (t + 1) * 64);
            asm volatile("s_waitcnt vmcnt(8)" ::: "memory");  // cur tile landed
        } else {
            asm volatile("s_waitcnt vmcnt(0)" ::: "memory");
        }
        __builtin_amdgcn_s_barrier();
        __builtin_amdgcn_sched_barrier(0);
        compute(cur);
        __builtin_amdgcn_sched_barrier(0);
        __builtin_amdgcn_s_barrier();   // readers done before buf reuse
    }

#pragma unroll
    for (int i = 0; i < 4; ++i) {
#pragma unroll
        for (int j = 0; j < 4; ++j) {
            int n = bn + n_base + j * 16 + l16;
            float bia = bias[n];
#pragma unroll
            for (int r = 0; r < 4; ++r) {
                int m = bm + m_base + i * 16 + lk * 4 + r;
                if (m < NNODES) {
                    float val = acc[i][j][r] + bia;
                    if (isb)
                        ((__hip_bfloat16*)Cv)[(size_t)m * ldc + n] = __float2bfloat16(val);
                    else
                        ((float*)Cv)[(size_t)m * ldc + n] = val;
                }
            }
        }
    }
}

// ---------------------------------------------------------------------------
// Wave-per-node fused z+r attention, 2-deep software pipeline.
// K2/V2 gate-packed [node][gate*256+ch]; S bf16.
__global__ __launch_bounds__(256) void attn_zr(
    const __hip_bfloat16* __restrict__ Qz, const __hip_bfloat16* __restrict__ Qr,
    const __hip_bfloat16* __restrict__ K2, const __hip_bfloat16* __restrict__ V2,
    const __hip_bfloat16* __restrict__ Sz, const __hip_bfloat16* __restrict__ Sr,
    const int* __restrict__ rowptr, const int* __restrict__ csrc,
    const float* __restrict__ h,
    float* __restrict__ Zout, __hip_bfloat16* __restrict__ abuf) {
    int lane = threadIdx.x & 63;
    int node = blockIdx.x * 4 + (threadIdx.x >> 6);

    int eA = lane >> 4;           // phase A edge slot
    int gA = (lane >> 3) & 1;     // phase A gate
    int hA = lane & 7;            // phase A head
    int gC = lane >> 5;           // phase C gate
    int cL = lane & 31;           // phase C channel group
    int cBase = cL * 8;
    int hC = cL >> 2;
    int wsrc = gC * 8 + hC;
    size_t kOff = (size_t)gA * 256 + hA * 32;   // within 512-ch packed row
    size_t vOff = (size_t)gC * 256 + cBase;

    const __hip_bfloat16* Qa = gA ? Qr : Qz;
    short8 qs[4];
    {
        const short8* Qrow = (const short8*)&Qa[(size_t)node * HIDC + hA * 32];
        qs[0] = Qrow[0]; qs[1] = Qrow[1]; qs[2] = Qrow[2]; qs[3] = Qrow[3];
    }

    int beg = rowptr[node], end = rowptr[node + 1];
    float acc[8] = {};
    float s_priv = 0.f;

    auto issueKV = [&](int snL, short8* k, short8* v) {
        int mySn = __shfl(snL, eA);
        const short8* Kp = (const short8*)&K2[(size_t)mySn * 512 + kOff];
        k[0] = Kp[0]; k[1] = Kp[1]; k[2] = Kp[2]; k[3] = Kp[3];
#pragma unroll
        for (int e = 0; e < 4; ++e) {
            int sne = __shfl(snL, e);
            v[e] = *(const short8*)&V2[(size_t)sne * 512 + vOff];
        }
    };
    auto computeC = [&](int snL, int cnt, short8* k, short8* v) {
        float w = 0.f;
        if (eA < cnt) {
            float dot = 0.f;
#pragma unroll
            for (int i = 0; i < 4; ++i) {
                short8 kv = k[i], qv = qs[i];
#pragma unroll
                for (int j = 0; j < 8; ++j)
                    dot += bfbits((unsigned short)qv[j]) * bfbits((unsigned short)kv[j]);
            }
            w = __expf(dot * SCALE);
        }
#pragma unroll
        for (int e = 0; e < 4; ++e) {
            float we = __shfl(w, e * 16 + wsrc);
            if (e < cnt) {
                short8 vv = v[e];
#pragma unroll
                for (int j = 0; j < 8; ++j) acc[j] += we * bfbits((unsigned short)vv[j]);
                s_priv += we;
            }
        }
    };

    if (beg < end) {
        short8 kA[4], vA[4], kB[4], vB[4];
        int baseA = beg;
        int cntA = min(4, end - baseA);
        int snLA = (lane < cntA) ? csrc[baseA + lane] : 0;
        issueKV(snLA, kA, vA);
        int baseB = baseA + 4, cntB = 0, snLB = 0;
        if (baseB < end) { cntB = min(4, end - baseB); snLB = (lane < cntB) ? csrc[baseB + lane] : 0; }
        for (;;) {
            if (baseB < end) issueKV(snLB, kB, vB);
            int baseN = baseB + 4, cntN = 0, snLN = 0;
            if (baseN < end) { cntN = min(4, end - baseN); snLN = (lane < cntN) ? csrc[baseN + lane] : 0; }
            computeC(snLA, cntA, kA, vA);
            if (baseB >= end) break;
            if (baseN < end) issueKV(snLN, kA, vA);
            int baseN2 = baseN + 4, cntN2 = 0, snLN2 = 0;
            if (baseN2 < end) { cntN2 = min(4, end - baseN2); snLN2 = (lane < cntN2) ? csrc[baseN2 + lane] : 0; }
            computeC(snLB, cntB, kB, vB);
            if (baseN >= end) break;
            baseA = baseN; cntA = cntN; snLA = snLN;
            baseB = baseN2; cntB = cntN2; snLB = snLN2;
        }
    }

    float inv = 1.f / (s_priv + 1e-16f);
    const __hip_bfloat16* Sx = gC ? Sr : Sz;
    short8 sv = *(const short8*)&Sx[(size_t)node * HIDC + cBase];
    float g[8];
#pragma unroll
    for (int j = 0; j < 8; ++j) {
        float p = acc[j] * inv + bfbits((unsigned short)sv[j]);
        g[j] = 1.f / (1.f + __expf(-p));
    }
    if (gC == 0) {
        float* Zp = &Zout[(size_t)node * HIDC + cBase];
#pragma unroll
        for (int j = 0; j < 8; ++j) Zp[j] = g[j];
    } else {
        const float* hp = &h[(size_t)node * HIDC + cBase];
        __hip_bfloat16* ap = &abuf[(size_t)node * DINC + HIDC + cBase];
#pragma unroll
        for (int j = 0; j < 8; ++j) ap[j] = __float2bfloat16(g[j] * hp[j]);
    }
}

// ---------------------------------------------------------------------------
// Wave-per-node c-gate attention + GRU combine, 2-deep pipeline. S bf16.
__global__ __launch_bounds__(256) void attn_c(
    const __hip_bfloat16* __restrict__ Q, const __hip_bfloat16* __restrict__ K,
    const __hip_bfloat16* __restrict__ V, const __hip_bfloat16* __restrict__ S,
    const int* __restrict__ rowptr, const int* __restrict__ csrc,
    const float* __restrict__ zbuf, const float* __restrict__ h,
    float* __restrict__ out) {
    int lane = threadIdx.x & 63;
    int node = blockIdx.x * 4 + (threadIdx.x >> 6);

    int eA = lane >> 3;           // phase A edge slot (0..7)
    int hA = lane & 7;            // phase A head
    int cBase = lane * 4;         // phase C: 4 channels per lane
    int hC = lane >> 3;           // head of phase C channels

    short8 qs[4];
    {
        const short8* Qrow = (const short8*)&Q[(size_t)node * HIDC + hA * 32];
        qs[0] = Qrow[0]; qs[1] = Qrow[1]; qs[2] = Qrow[2]; qs[3] = Qrow[3];
    }

    int beg = rowptr[node], end = rowptr[node + 1];
    float acc[4] = {};
    float s_priv = 0.f;

    auto issueKV = [&](int snL, short8* k, svec4* v) {
        int mySn = __shfl(snL, eA);
        const short8* Kp = (const short8*)&K[(size_t)mySn * HIDC + hA * 32];
        k[0] = Kp[0]; k[1] = Kp[1]; k[2] = Kp[2]; k[3] = Kp[3];
#pragma unroll
        for (int e = 0; e < 8; ++e) {
            int sne = __shfl(snL, e);
            v[e] = *(const svec4*)&V[(size_t)sne * HIDC + cBase];
        }
    };
    auto computeC = [&](int snL, int cnt, short8* k, svec4* v) {
        float w = 0.f;
        if (eA < cnt) {
            float dot = 0.f;
#pragma unroll
            for (int i = 0; i < 4; ++i) {
                short8 kv = k[i], qv = qs[i];
#pragma unroll
                for (int j = 0; j < 8; ++j)
                    dot += bfbits((unsigned short)qv[j]) * bfbits((unsigned short)kv[j]);
            }
            w = __expf(dot * SCALE);
        }
#pragma unroll
        for (int e = 0; e < 8; ++e) {
            float we = __shfl(w, e * 8 + hC);
            if (e < cnt) {
                svec4 vv = v[e];
#pragma unroll
                for (int j = 0; j < 4; ++j) acc[j] += we * bfbits((unsigned short)vv[j]);
                s_priv += we;
            }
        }
    };

    if (beg < end) {
        short8 kA[4], kB[4];
        svec4 vA[8], vB[8];
        int baseA = beg;
        int cntA = min(8, end - baseA);
        int snLA = (lane < cntA) ? csrc[baseA + lane] : 0;
        issueKV(snLA, kA, vA);
        int baseB = baseA + 8, cntB = 0, snLB = 0;
        if (baseB < end) { cntB = min(8, end - baseB); snLB = (lane < cntB) ? csrc[baseB + lane] : 0; }
        for (;;) {
            if (baseB < end) issueKV(snLB, kB, vB);
            int baseN = baseB + 8, cntN = 0, snLN = 0;
            if (baseN < end) { cntN = min(8, end - baseN); snLN = (lane < cntN) ? csrc[baseN + lane] : 0; }
            computeC(snLA, cntA, kA, vA);
            if (baseB >= end) break;
            if (baseN < end) issueKV(snLN, kA, vA);
            int baseN2 = baseN + 8, cntN2 = 0, snLN2 = 0;
            if (baseN2 < end) { cntN2 = min(8, end - baseN2); snLN2 = (lane < cntN2) ? csrc[baseN2 + lane] : 0; }
            computeC(snLB, cntB, kB, vB);
            if (baseN >= end) break;
            baseA = baseN; cntA = cntN; snLA = snLN;
            baseB = baseN2; cntB = cntN2; snLB = snLN2;
        }
    }

    float inv = 1.f / (s_priv + 1e-16f);
    svec4 sv = *(const svec4*)&S[(size_t)node * HIDC + cBase];
    f32x4 o;
#pragma unroll
    for (int j = 0; j < 4; ++j) {
        float pre = acc[j] * inv + bfbits((unsigned short)sv[j]);
        float ht = tanhf(pre);
        float zz = zbuf[(size_t)node * HIDC + cBase + j];
        float hh = h[(size_t)node * HIDC + cBase + j];
        o[j] = zz * hh + (1.f - zz) * ht;
    }
    *(f32x4*)&out[(size_t)node * HIDC + cBase] = o;
}

// ---------------------------------------------------------------------------
extern "C" void kernel_launch(void* const* d_in, const int* in_sizes, int n_in,
                              void* d_out, int out_size, void* d_ws, size_t ws_size,
                              hipStream_t stream) {
    const float* x = (const float*)d_in[0];
    const float* h = (const float*)d_in[1];
    const int* ei = (const int*)d_in[2];
    const float* Wf[3][4];
    const float* B[3][4];
    for (int g = 0; g < 3; ++g)
        for (int p = 0; p < 4; ++p) {
            Wf[g][p] = (const float*)d_in[3 + g * 8 + p * 2];
            B[g][p] = (const float*)d_in[3 + g * 8 + p * 2 + 1];
        }

    char* ws = (char*)d_ws;
    size_t off = 0;
    auto alloc = [&](size_t bytes) {
        void* p = ws + off;
        off = (off + bytes + 255) & ~(size_t)255;
        return p;
    };
    __hip_bfloat16* Abuf = (__hip_bfloat16*)alloc((size_t)MPAD * DINC * 2);
    __hip_bfloat16* Wt = (__hip_bfloat16*)alloc((size_t)12 * HIDC * DINC * 2);
    __hip_bfloat16* Qz = (__hip_bfloat16*)alloc((size_t)NNODES * HIDC * 2);
    __hip_bfloat16* Qr = (__hip_bfloat16*)alloc((size_t)NNODES * HIDC * 2);
    __hip_bfloat16* K2 = (__hip_bfloat16*)alloc((size_t)NNODES * 512 * 2);  // Kz|Kr packed
    __hip_bfloat16* V2 = (__hip_bfloat16*)alloc((size_t)NNODES * 512 * 2);  // Vz|Vr packed
    __hip_bfloat16* Sz = (__hip_bfloat16*)alloc((size_t)NNODES * HIDC * 2);
    __hip_bfloat16* Sr = (__hip_bfloat16*)alloc((size_t)NNODES * HIDC * 2);
    float* Zb = (float*)alloc((size_t)NNODES * HIDC * 4);
    int* deg = (int*)alloc((size_t)NNODES * 4);
    int* rowptr = (int*)alloc((size_t)(NNODES + 1) * 4);
    int* pos = (int*)alloc((size_t)NNODES * 4);
    int* csrc = (int*)alloc((size_t)NEDGES * 4);

    const int* srcArr = ei;
    const int* dstArr = ei + NEDGES;

    WPtrs wp;
    for (int g = 0; g < 3; ++g)
        for (int p = 0; p < 4; ++p) wp.p[g * 4 + p] = Wf[g][p];

    (void)hipMemsetAsync(deg, 0, NNODES * sizeof(int), stream);
    concat_xh<<<(MPAD * DINC + 255) / 256, 256, 0, stream>>>(x, h, Abuf);
    transpose_w<<<dim3(8, 4, 12), 256, 0, stream>>>(wp, Wt);
    count_deg<<<(NEDGES + 255) / 256, 256, 0, stream>>>(dstArr, deg);
    exscan<<<1, 1024, 0, stream>>>(deg, rowptr, pos);
    scatter_src<<<(NEDGES + 255) / 256, 256, 0, stream>>>(srcArr, dstArr, pos, csrc);

    // GEMM launch A: z+r gates, 8 matrices; grid = 157 * 16 = 2512 (div by 8)
    {
        GemmArgs ga;
        for (int p = 0; p < 4; ++p) { ga.bias[p] = B[0][p]; ga.bias[4 + p] = B[1][p]; }
        ga.C[0] = Qz;        ga.ldc[0] = 256;
        ga.C[1] = K2;        ga.ldc[1] = 512;   // Kz -> packed row low half
        ga.C[2] = V2;        ga.ldc[2] = 512;
        ga.C[3] = Sz;        ga.ldc[3] = 256;
        ga.C[4] = Qr;        ga.ldc[4] = 256;
        ga.C[5] = K2 + 256;  ga.ldc[5] = 512;   // Kr -> packed row high half
        ga.C[6] = V2 + 256;  ga.ldc[6] = 512;
        ga.C[7] = Sr;        ga.ldc[7] = 256;
        ga.bf16mask = 0xFF;
        gemm_mfma<16><<<(MPAD / 128) * 16, 256, 0, stream>>>(Abuf, Wt, ga);
    }
    attn_zr<<<NNODES / 4, 256, 0, stream>>>(Qz, Qr, K2, V2, Sz, Sr,
                                            rowptr, csrc, h, Zb, Abuf);
    // GEMM launch B: c gate, 4 matrices; grid = 157 * 8 = 1256 (div by 8)
    {
        GemmArgs ga;
        for (int p = 0; p < 8; ++p) { ga.bias[p] = B[2][p & 3]; ga.C[p] = nullptr; ga.ldc[p] = 256; }
        ga.C[0] = Qz; ga.C[1] = K2; ga.C[2] = V2; ga.C[3] = Sz;   // reuse, ld 256 dense
        ga.bf16mask = 0xFF;
        gemm_mfma<8><<<(MPAD / 128) * 8, 256, 0, stream>>>(
            Abuf, Wt + (size_t)8 * HIDC * DINC, ga);
    }
    attn_c<<<NNODES / 4, 256, 0, stream>>>(Qz, K2, V2, Sz, rowptr, csrc,
                                           Zb, h, (float*)d_out);
}

// Round 12
// 345.819 us; speedup vs baseline: 1.1674x; 1.0586x over previous
//
#include <hip/hip_runtime.h>
#include <hip/hip_bf16.h>
#include <math.h>

#define NNODES 20000
#define MPAD 20096            // multiple of 128 (and 64)
#define NEDGES 320000
#define HIDC 256
#define DINC 512
#define NHEAD 8
#define HDIM 32
#define SCALE 0.17677669529663687f

typedef __attribute__((ext_vector_type(8))) short short8;
typedef __attribute__((ext_vector_type(4))) short svec4;
typedef __attribute__((ext_vector_type(4))) float f32x4;

__device__ __forceinline__ void gload_lds16(const void* g, void* l) {
    __builtin_amdgcn_global_load_lds(
        (const __attribute__((address_space(1))) unsigned int*)g,
        (__attribute__((address_space(3))) unsigned int*)l, 16, 0, 0);
}

__device__ __forceinline__ float bfbits(unsigned short u) {
    return __uint_as_float(((unsigned)u) << 16);
}

// ---------------------------------------------------------------------------
// concat h_in = [x | h] -> bf16 [MPAD][512], pad rows zeroed
__global__ __launch_bounds__(256) void concat_xh(const float* __restrict__ x,
                                                 const float* __restrict__ h,
                                                 __hip_bfloat16* __restrict__ out) {
    int i = blockIdx.x * 256 + threadIdx.x;
    int total = MPAD * DINC;
    if (i >= total) return;
    int row = i >> 9;
    int col = i & 511;
    float v = 0.f;
    if (row < NNODES)
        v = (col < HIDC) ? x[row * HIDC + col] : h[row * HIDC + (col - HIDC)];
    out[i] = __float2bfloat16(v);
}

// ---------------------------------------------------------------------------
// weight transpose+convert: W[512][256] f32 -> Wt[256][512] bf16 (12 matrices)
struct WPtrs { const float* p[12]; };

__global__ __launch_bounds__(256) void transpose_w(WPtrs wp, __hip_bfloat16* __restrict__ out) {
    __shared__ float t[64][65];
    int mat = blockIdx.z;
    int kt = blockIdx.x * 64;
    int nt = blockIdx.y * 64;
    const float* W = wp.p[mat];
    int c = threadIdx.x & 63, r4 = threadIdx.x >> 6;
#pragma unroll
    for (int rr = 0; rr < 16; ++rr) {
        int k_l = r4 + rr * 4;
        t[k_l][c] = W[(kt + k_l) * HIDC + nt + c];
    }
    __syncthreads();
#pragma unroll
    for (int rr = 0; rr < 16; ++rr) {
        int n_l = r4 + rr * 4;
        out[mat * (HIDC * DINC) + (nt + n_l) * DINC + kt + c] =
            __float2bfloat16(t[c][n_l]);
    }
}

// ---------------------------------------------------------------------------
// CSR build (stores src node directly: csrc[idx] = src[e])
__global__ __launch_bounds__(256) void count_deg(const int* __restrict__ dst,
                                                 int* __restrict__ deg) {
    int e = blockIdx.x * 256 + threadIdx.x;
    if (e >= NEDGES) return;
    atomicAdd(&deg[dst[e]], 1);
}

// wave-shuffle exclusive scan
__global__ __launch_bounds__(1024) void exscan(const int* __restrict__ deg,
                                               int* __restrict__ rowptr,
                                               int* __restrict__ pos) {
    __shared__ int wsum[16];
    __shared__ int s_carry;
    const int tid = threadIdx.x;
    const int lane = tid & 63, wid = tid >> 6;
    if (tid == 0) { s_carry = 0; rowptr[0] = 0; }
    __syncthreads();
    for (int base = 0; base < NNODES; base += 1024) {
        int i = base + tid;
        int v = (i < NNODES) ? deg[i] : 0;
        int s = v;
#pragma unroll
        for (int off = 1; off < 64; off <<= 1) {
            int t = __shfl_up(s, off);
            if (lane >= off) s += t;
        }
        if (lane == 63) wsum[wid] = s;
        __syncthreads();
        if (wid == 0 && lane < 16) {
            int ws = wsum[lane];
#pragma unroll
            for (int off = 1; off < 16; off <<= 1) {
                int t = __shfl_up(ws, off);
                if (lane >= off) ws += t;
            }
            wsum[lane] = ws;
        }
        __syncthreads();
        int woff = (wid > 0) ? wsum[wid - 1] : 0;
        int incl = s + woff + s_carry;
        if (i < NNODES) {
            rowptr[i] = incl - v;
            pos[i] = incl - v;
            if (i == NNODES - 1) rowptr[NNODES] = incl;
        }
        __syncthreads();
        if (tid == 1023) s_carry = incl;
        __syncthreads();
    }
}

__global__ __launch_bounds__(256) void scatter_src(const int* __restrict__ src,
                                                   const int* __restrict__ dst,
                                                   int* __restrict__ pos,
                                                   int* __restrict__ csrc) {
    int e = blockIdx.x * 256 + threadIdx.x;
    if (e >= NEDGES) return;
    int idx = atomicAdd(&pos[dst[e]], 1);
    csrc[idx] = src[e];
}

// ---------------------------------------------------------------------------
// MFMA GEMM, 64x128 tile, double-buffered 48KB LDS (3 blocks/CU = 12 waves/CU)
// + counted vmcnt(6); XCD-contiguous mapping for A-tile L2 reuse.
// Per-slot C pointer + ldc + bf16 mask.
struct GemmArgs { const float* bias[8]; void* C[8]; int ldc[8]; unsigned bf16mask; };

template <int NZ>
__global__ __launch_bounds__(256) void gemm_mfma(
    const __hip_bfloat16* __restrict__ A,
    const __hip_bfloat16* __restrict__ WtBase,
    GemmArgs ga) {
    __shared__ __align__(16) char smem[2][24576];  // [buf][A 8KB | B 16KB]

    int nwg = gridDim.x;
    int per = nwg >> 3;
    int lin = (blockIdx.x & 7) * per + (blockIdx.x >> 3);  // XCD-contiguous
    int bmIdx = lin / NZ;
    int nz = lin % NZ;
    int bm = bmIdx * 64;
    int bn = (nz & 1) * 128;
    int z = nz >> 1;

    const __hip_bfloat16* Bt = WtBase + (size_t)z * (HIDC * DINC);
    const float* bias = ga.bias[z];
    void* Cv = ga.C[z];
    int ldc = ga.ldc[z];
    bool isb = (ga.bf16mask >> z) & 1;

    int tid = threadIdx.x;
    int wave = tid >> 6, lane = tid & 63;
    int lrow = lane >> 3;                 // 0..7
    int lcol = (lane & 7) ^ lrow;         // pre-swizzled source column unit

    int wr = wave >> 1, wc = wave & 1;
    int m_base = wr * 32, n_base = wc * 64;
    int l16 = lane & 15, lk = lane >> 4;

    f32x4 acc[2][4] = {};

    auto stage = [&](int buf, int kt) {
        char* As = smem[buf];
        char* Bs = smem[buf] + 8192;
#pragma unroll
        for (int c4 = 0; c4 < 2; ++c4) {         // A: 8 chunks of 8 rows
            int c = wave * 2 + c4;
            gload_lds16(&A[(size_t)(bm + c * 8 + lrow) * DINC + kt + lcol * 8],
                        As + c * 1024);
        }
#pragma unroll
        for (int c4 = 0; c4 < 4; ++c4) {         // B: 16 chunks of 8 rows
            int c = wave * 4 + c4;
            gload_lds16(&Bt[(size_t)(bn + c * 8 + lrow) * DINC + kt + lcol * 8],
                        Bs + c * 1024);
        }
    };

    auto compute = [&](int buf) {
        char* As = smem[buf];
        char* Bs = smem[buf] + 8192;
#pragma unroll
        for (int kk = 0; kk < 2; ++kk) {
            short8 af[2], bf[4];
#pragma unroll
            for (int f = 0; f < 2; ++f) {
                int row = m_base + f * 16 + l16;
                int lin2 = row * 128 + (kk * 32 + lk * 8) * 2;
                af[f] = *(const short8*)(As + (lin2 ^ ((row & 7) << 4)));
            }
#pragma unroll
            for (int f = 0; f < 4; ++f) {
                int rowb = n_base + f * 16 + l16;
                int linb = rowb * 128 + (kk * 32 + lk * 8) * 2;
                bf[f] = *(const short8*)(Bs + (linb ^ ((rowb & 7) << 4)));
            }
#pragma unroll
            for (int i = 0; i < 2; ++i)
#pragma unroll
                for (int j = 0; j < 4; ++j)
                    acc[i][j] = __builtin_amdgcn_mfma_f32_16x16x32_bf16(
                        af[i], bf[j], acc[i][j], 0, 0, 0);
        }
    };

    stage(0, 0);
#pragma unroll
    for (int t = 0; t < 8; ++t) {
        int cur = t & 1;
        if (t < 7) {
            stage(cur ^ 1, (t + 1) * 64);
            asm volatile("s_waitcnt vmcnt(6)" ::: "memory");  // cur tile landed
        } else {
            asm volatile("s_waitcnt vmcnt(0)" ::: "memory");
        }
        __builtin_amdgcn_s_barrier();
        __builtin_amdgcn_sched_barrier(0);
        compute(cur);
        __builtin_amdgcn_sched_barrier(0);
        __builtin_amdgcn_s_barrier();   // readers done before buf reuse
    }

#pragma unroll
    for (int i = 0; i < 2; ++i) {
#pragma unroll
        for (int j = 0; j < 4; ++j) {
            int n = bn + n_base + j * 16 + l16;
            float bia = bias[n];
#pragma unroll
            for (int r = 0; r < 4; ++r) {
                int m = bm + m_base + i * 16 + lk * 4 + r;
                if (m < NNODES) {
                    float val = acc[i][j][r] + bia;
                    if (isb)
                        ((__hip_bfloat16*)Cv)[(size_t)m * ldc + n] = __float2bfloat16(val);
                    else
                        ((float*)Cv)[(size_t)m * ldc + n] = val;
                }
            }
        }
    }
}

// ---------------------------------------------------------------------------
// Wave-per-node fused z+r attention, 2-deep software pipeline.
// K2/V2 gate-packed bf16 [node][gate*256+ch]; S bf16.
__global__ __launch_bounds__(256) void attn_zr(
    const __hip_bfloat16* __restrict__ Qz, const __hip_bfloat16* __restrict__ Qr,
    const __hip_bfloat16* __restrict__ K2, const __hip_bfloat16* __restrict__ V2,
    const __hip_bfloat16* __restrict__ Sz, const __hip_bfloat16* __restrict__ Sr,
    const int* __restrict__ rowptr, const int* __restrict__ csrc,
    const float* __restrict__ h,
    float* __restrict__ Zout, __hip_bfloat16* __restrict__ abuf) {
    int lane = threadIdx.x & 63;
    int node = blockIdx.x * 4 + (threadIdx.x >> 6);

    int eA = lane >> 4;           // phase A edge slot
    int gA = (lane >> 3) & 1;     // phase A gate
    int hA = lane & 7;            // phase A head
    int gC = lane >> 5;           // phase C gate
    int cL = lane & 31;           // phase C channel group
    int cBase = cL * 8;
    int hC = cL >> 2;
    int wsrc = gC * 8 + hC;
    size_t kOff = (size_t)gA * 256 + hA * 32;   // within 512-ch packed row
    size_t vOff = (size_t)gC * 256 + cBase;

    const __hip_bfloat16* Qa = gA ? Qr : Qz;
    short8 qs[4];
    {
        const short8* Qrow = (const short8*)&Qa[(size_t)node * HIDC + hA * 32];
        qs[0] = Qrow[0]; qs[1] = Qrow[1]; qs[2] = Qrow[2]; qs[3] = Qrow[3];
    }

    int beg = rowptr[node], end = rowptr[node + 1];
    float acc[8] = {};
    float s_priv = 0.f;

    auto issueKV = [&](int snL, short8* k, short8* v) {
        int mySn = __shfl(snL, eA);
        const short8* Kp = (const short8*)&K2[(size_t)mySn * 512 + kOff];
        k[0] = Kp[0]; k[1] = Kp[1]; k[2] = Kp[2]; k[3] = Kp[3];
#pragma unroll
        for (int e = 0; e < 4; ++e) {
            int sne = __shfl(snL, e);
            v[e] = *(const short8*)&V2[(size_t)sne * 512 + vOff];
        }
    };
    auto computeC = [&](int snL, int cnt, short8* k, short8* v) {
        float w = 0.f;
        if (eA < cnt) {
            float dot = 0.f;
#pragma unroll
            for (int i = 0; i < 4; ++i) {
                short8 kv = k[i], qv = qs[i];
#pragma unroll
                for (int j = 0; j < 8; ++j)
                    dot += bfbits((unsigned short)qv[j]) * bfbits((unsigned short)kv[j]);
            }
            w = __expf(dot * SCALE);
        }
#pragma unroll
        for (int e = 0; e < 4; ++e) {
            float we = __shfl(w, e * 16 + wsrc);
            if (e < cnt) {
                short8 vv = v[e];
#pragma unroll
                for (int j = 0; j < 8; ++j) acc[j] += we * bfbits((unsigned short)vv[j]);
                s_priv += we;
            }
        }
    };

    if (beg < end) {
        short8 kA[4], vA[4], kB[4], vB[4];
        int baseA = beg;
        int cntA = min(4, end - baseA);
        int snLA = (lane < cntA) ? csrc[baseA + lane] : 0;
        issueKV(snLA, kA, vA);
        int baseB = baseA + 4, cntB = 0, snLB = 0;
        if (baseB < end) { cntB = min(4, end - baseB); snLB = (lane < cntB) ? csrc[baseB + lane] : 0; }
        for (;;) {
            if (baseB < end) issueKV(snLB, kB, vB);
            int baseN = baseB + 4, cntN = 0, snLN = 0;
            if (baseN < end) { cntN = min(4, end - baseN); snLN = (lane < cntN) ? csrc[baseN + lane] : 0; }
            computeC(snLA, cntA, kA, vA);
            if (baseB >= end) break;
            if (baseN < end) issueKV(snLN, kA, vA);
            int baseN2 = baseN + 4, cntN2 = 0, snLN2 = 0;
            if (baseN2 < end) { cntN2 = min(4, end - baseN2); snLN2 = (lane < cntN2) ? csrc[baseN2 + lane] : 0; }
            computeC(snLB, cntB, kB, vB);
            if (baseN >= end) break;
            baseA = baseN; cntA = cntN; snLA = snLN;
            baseB = baseN2; cntB = cntN2; snLB = snLN2;
        }
    }

    float inv = 1.f / (s_priv + 1e-16f);
    const __hip_bfloat16* Sx = gC ? Sr : Sz;
    short8 sv = *(const short8*)&Sx[(size_t)node * HIDC + cBase];
    float g[8];
#pragma unroll
    for (int j = 0; j < 8; ++j) {
        float p = acc[j] * inv + bfbits((unsigned short)sv[j]);
        g[j] = 1.f / (1.f + __expf(-p));
    }
    if (gC == 0) {
        float* Zp = &Zout[(size_t)node * HIDC + cBase];
#pragma unroll
        for (int j = 0; j < 8; ++j) Zp[j] = g[j];
    } else {
        const float* hp = &h[(size_t)node * HIDC + cBase];
        __hip_bfloat16* ap = &abuf[(size_t)node * DINC + HIDC + cBase];
#pragma unroll
        for (int j = 0; j < 8; ++j) ap[j] = __float2bfloat16(g[j] * hp[j]);
    }
}

// ---------------------------------------------------------------------------
// Wave-per-node c-gate attention + GRU combine, 2-deep pipeline. S bf16.
__global__ __launch_bounds__(256) void attn_c(
    const __hip_bfloat16* __restrict__ Q, const __hip_bfloat16* __restrict__ K,
    const __hip_bfloat16* __restrict__ V, const __hip_bfloat16* __restrict__ S,
    const int* __restrict__ rowptr, const int* __restrict__ csrc,
    const float* __restrict__ zbuf, const float* __restrict__ h,
    float* __restrict__ out) {
    int lane = threadIdx.x & 63;
    int node = blockIdx.x * 4 + (threadIdx.x >> 6);

    int eA = lane >> 3;           // phase A edge slot (0..7)
    int hA = lane & 7;            // phase A head
    int cBase = lane * 4;         // phase C: 4 channels per lane
    int hC = lane >> 3;           // head of phase C channels

    short8 qs[4];
    {
        const short8* Qrow = (const short8*)&Q[(size_t)node * HIDC + hA * 32];
        qs[0] = Qrow[0]; qs[1] = Qrow[1]; qs[2] = Qrow[2]; qs[3] = Qrow[3];
    }

    int beg = rowptr[node], end = rowptr[node + 1];
    float acc[4] = {};
    float s_priv = 0.f;

    auto issueKV = [&](int snL, short8* k, svec4* v) {
        int mySn = __shfl(snL, eA);
        const short8* Kp = (const short8*)&K[(size_t)mySn * HIDC + hA * 32];
        k[0] = Kp[0]; k[1] = Kp[1]; k[2] = Kp[2]; k[3] = Kp[3];
#pragma unroll
        for (int e = 0; e < 8; ++e) {
            int sne = __shfl(snL, e);
            v[e] = *(const svec4*)&V[(size_t)sne * HIDC + cBase];
        }
    };
    auto computeC = [&](int snL, int cnt, short8* k, svec4* v) {
        float w = 0.f;
        if (eA < cnt) {
            float dot = 0.f;
#pragma unroll
            for (int i = 0; i < 4; ++i) {
                short8 kv = k[i], qv = qs[i];
#pragma unroll
                for (int j = 0; j < 8; ++j)
                    dot += bfbits((unsigned short)qv[j]) * bfbits((unsigned short)kv[j]);
            }
            w = __expf(dot * SCALE);
        }
#pragma unroll
        for (int e = 0; e < 8; ++e) {
            float we = __shfl(w, e * 8 + hC);
            if (e < cnt) {
                svec4 vv = v[e];
#pragma unroll
                for (int j = 0; j < 4; ++j) acc[j] += we * bfbits((unsigned short)vv[j]);
                s_priv += we;
            }
        }
    };

    if (beg < end) {
        short8 kA[4], kB[4];
        svec4 vA[8], vB[8];
        int baseA = beg;
        int cntA = min(8, end - baseA);
        int snLA = (lane < cntA) ? csrc[baseA + lane] : 0;
        issueKV(snLA, kA, vA);
        int baseB = baseA + 8, cntB = 0, snLB = 0;
        if (baseB < end) { cntB = min(8, end - baseB); snLB = (lane < cntB) ? csrc[baseB + lane] : 0; }
        for (;;) {
            if (baseB < end) issueKV(snLB, kB, vB);
            int baseN = baseB + 8, cntN = 0, snLN = 0;
            if (baseN < end) { cntN = min(8, end - baseN); snLN = (lane < cntN) ? csrc[baseN + lane] : 0; }
            computeC(snLA, cntA, kA, vA);
            if (baseB >= end) break;
            if (baseN < end) issueKV(snLN, kA, vA);
            int baseN2 = baseN + 8, cntN2 = 0, snLN2 = 0;
            if (baseN2 < end) { cntN2 = min(8, end - baseN2); snLN2 = (lane < cntN2) ? csrc[baseN2 + lane] : 0; }
            computeC(snLB, cntB, kB, vB);
            if (baseN >= end) break;
            baseA = baseN; cntA = cntN; snLA = snLN;
            baseB = baseN2; cntB = cntN2; snLB = snLN2;
        }
    }

    float inv = 1.f / (s_priv + 1e-16f);
    svec4 sv = *(const svec4*)&S[(size_t)node * HIDC + cBase];
    f32x4 o;
#pragma unroll
    for (int j = 0; j < 4; ++j) {
        float pre = acc[j] * inv + bfbits((unsigned short)sv[j]);
        float ht = tanhf(pre);
        float zz = zbuf[(size_t)node * HIDC + cBase + j];
        float hh = h[(size_t)node * HIDC + cBase + j];
        o[j] = zz * hh + (1.f - zz) * ht;
    }
    *(f32x4*)&out[(size_t)node * HIDC + cBase] = o;
}

// ---------------------------------------------------------------------------
extern "C" void kernel_launch(void* const* d_in, const int* in_sizes, int n_in,
                              void* d_out, int out_size, void* d_ws, size_t ws_size,
                              hipStream_t stream) {
    const float* x = (const float*)d_in[0];
    const float* h = (const float*)d_in[1];
    const int* ei = (const int*)d_in[2];
    const float* Wf[3][4];
    const float* B[3][4];
    for (int g = 0; g < 3; ++g)
        for (int p = 0; p < 4; ++p) {
            Wf[g][p] = (const float*)d_in[3 + g * 8 + p * 2];
            B[g][p] = (const float*)d_in[3 + g * 8 + p * 2 + 1];
        }

    char* ws = (char*)d_ws;
    size_t off = 0;
    auto alloc = [&](size_t bytes) {
        void* p = ws + off;
        off = (off + bytes + 255) & ~(size_t)255;
        return p;
    };
    __hip_bfloat16* Abuf = (__hip_bfloat16*)alloc((size_t)MPAD * DINC * 2);
    __hip_bfloat16* Wt = (__hip_bfloat16*)alloc((size_t)12 * HIDC * DINC * 2);
    __hip_bfloat16* Qz = (__hip_bfloat16*)alloc((size_t)NNODES * HIDC * 2);
    __hip_bfloat16* Qr = (__hip_bfloat16*)alloc((size_t)NNODES * HIDC * 2);
    __hip_bfloat16* K2 = (__hip_bfloat16*)alloc((size_t)NNODES * 512 * 2);  // Kz|Kr packed
    __hip_bfloat16* V2 = (__hip_bfloat16*)alloc((size_t)NNODES * 512 * 2);  // Vz|Vr packed
    __hip_bfloat16* Sz = (__hip_bfloat16*)alloc((size_t)NNODES * HIDC * 2);
    __hip_bfloat16* Sr = (__hip_bfloat16*)alloc((size_t)NNODES * HIDC * 2);
    float* Zb = (float*)alloc((size_t)NNODES * HIDC * 4);
    int* deg = (int*)alloc((size_t)NNODES * 4);
    int* rowptr = (int*)alloc((size_t)(NNODES + 1) * 4);
    int* pos = (int*)alloc((size_t)NNODES * 4);
    int* csrc = (int*)alloc((size_t)NEDGES * 4);

    const int* srcArr = ei;
    const int* dstArr = ei + NEDGES;

    WPtrs wp;
    for (int g = 0; g < 3; ++g)
        for (int p = 0; p < 4; ++p) wp.p[g * 4 + p] = Wf[g][p];

    (void)hipMemsetAsync(deg, 0, NNODES * sizeof(int), stream);
    concat_xh<<<(MPAD * DINC + 255) / 256, 256, 0, stream>>>(x, h, Abuf);
    transpose_w<<<dim3(8, 4, 12), 256, 0, stream>>>(wp, Wt);
    count_deg<<<(NEDGES + 255) / 256, 256, 0, stream>>>(dstArr, deg);
    exscan<<<1, 1024, 0, stream>>>(deg, rowptr, pos);
    scatter_src<<<(NEDGES + 255) / 256, 256, 0, stream>>>(srcArr, dstArr, pos, csrc);

    // GEMM launch A: z+r gates, 8 matrices; grid = 314 * 16 = 5024 (div by 8)
    {
        GemmArgs ga;
        for (int p = 0; p < 4; ++p) { ga.bias[p] = B[0][p]; ga.bias[4 + p] = B[1][p]; }
        ga.C[0] = Qz;        ga.ldc[0] = 256;
        ga.C[1] = K2;        ga.ldc[1] = 512;   // Kz -> packed row low half
        ga.C[2] = V2;        ga.ldc[2] = 512;
        ga.C[3] = Sz;        ga.ldc[3] = 256;
        ga.C[4] = Qr;        ga.ldc[4] = 256;
        ga.C[5] = K2 + 256;  ga.ldc[5] = 512;   // Kr -> packed row high half
        ga.C[6] = V2 + 256;  ga.ldc[6] = 512;
        ga.C[7] = Sr;        ga.ldc[7] = 256;
        ga.bf16mask = 0xFF;
        gemm_mfma<16><<<(MPAD / 64) * 16, 256, 0, stream>>>(Abuf, Wt, ga);
    }
    attn_zr<<<NNODES / 4, 256, 0, stream>>>(Qz, Qr, K2, V2, Sz, Sr,
                                            rowptr, csrc, h, Zb, Abuf);
    // GEMM launch B: c gate, 4 matrices; grid = 314 * 8 = 2512 (div by 8)
    {
        GemmArgs ga;
        for (int p = 0; p < 8; ++p) { ga.bias[p] = B[2][p & 3]; ga.C[p] = nullptr; ga.ldc[p] = 256; }
        ga.C[0] = Qz; ga.C[1] = K2; ga.C[2] = V2; ga.C[3] = Sz;   // reuse, ld 256 dense
        ga.bf16mask = 0xFF;
        gemm_mfma<8><<<(MPAD / 64) * 8, 256, 0, stream>>>(
            Abuf, Wt + (size_t)8 * HIDC * DINC, ga);
    }
    attn_c<<<NNODES / 4, 256, 0, stream>>>(Qz, K2, V2, Sz, rowptr, csrc,
                                           Zb, h, (float*)d_out);
}